// Round 12
// baseline (49449.390 us; speedup 1.0000x reference)
//
#include <hip/hip_runtime.h>
#include <hip/hip_bf16.h>

// ContinuousRecurrentCore (liquid-time-constant net) on MI355X.
//
// R12 = R7 resubmitted (5th GPUAcquisitionTimeout in a row; design frozen
// until it actually executes — no blind edits to an untested sync template).
// Pipelined 256x256 GEMM core. BK=32 (64B LDS rows -> ds_read_b128 at the
// 8-beat wave64 floor, conflict-free by layout), 512 threads / 8 waves
// (2M x 4N), 3-deep LDS ring (96KB), ONE raw s_barrier per K-tile,
// counted s_waitcnt vmcnt(4) (never 0 in main loop; peeled last iter),
// stage-issue AFTER the barrier (write-after-read safe: target buffer's
// readers finished >=1 barrier earlier), setprio(1) around MFMA cluster.
// Numerics (R6-validated, absmax floor = bf16 hi/lo state storage):
// A at fp32 via hi/lo split, W at bf16; 4 passes over 2 stored W blocks.
// N=2048 packs tau/forc columns alternating at 16-col granularity ->
// (tau,forc) pairs land in the same thread's C-fragments (no cross-lane
// epilogue). Device-side early-exit preserves freeze/t_conv semantics.
// All buffers in static __device__ globals (R4 d_ws-overflow crash fix).

typedef __attribute__((ext_vector_type(8))) short bf16x8s;
typedef __attribute__((ext_vector_type(4))) float f32x4;

constexpr int HD = 1024;       // hidden dim
constexpr int MR = 8192;       // B*S rows
constexpr int NLAYER = 4;
constexpr int MAXT = 50;
constexpr float DTC = 0.05f;
constexpr float EPS_TAU_C = 1e-6f;
constexpr float EPS_CONV_C = 1e-3f;

constexpr int BM = 256, BN = 256, BK = 32;
constexpr int KSTORE = 2048;   // 2 stored K-blocks of 1024: [Wx_hi, Wh_hi]
constexpr int NPACK = 2048;    // tau/forc interleaved at 16-col granularity
constexpr int NKT = 128;       // K-tile iterations: 4 passes x 32 tiles of 32
constexpr size_t WP_PER_LAYER = (size_t)64 * 8 * BN * BK;  // 4.19M elem
constexpr size_t HN = (size_t)MR * HD;

struct Ctrl {
  unsigned int done;
  int t_conv;
  unsigned int delta[MAXT];
};

// ---------------------------------------------------------- static workspace
__device__ __align__(16) __hip_bfloat16 g_Wp[NLAYER * WP_PER_LAYER];   // 33.5MB
__device__ __align__(16) __hip_bfloat16 g_xhi[HN];                     // 16.8MB
__device__ __align__(16) __hip_bfloat16 g_xlo[HN];                     // 16.8MB
__device__ __align__(16) __hip_bfloat16 g_h_hi[2 * NLAYER * HN];       // 134MB
__device__ __align__(16) __hip_bfloat16 g_h_lo[2 * NLAYER * HN];       // 134MB
__device__ float g_btau[NLAYER * HD];
__device__ float g_bforc[NLAYER * HD];
__device__ Ctrl g_ctrl;

__device__ __forceinline__ void gload_lds16(const __hip_bfloat16* g, __hip_bfloat16* lds) {
  __builtin_amdgcn_global_load_lds(
      (const __attribute__((address_space(1))) unsigned int*)g,
      (__attribute__((address_space(3))) unsigned int*)lds, 16, 0, 0);
}

// Branch-free tanh (~1e-6 abs err, below state-storage floor 2.4e-4).
__device__ __forceinline__ float fast_tanh(float x) {
  float t = __expf(-2.0f * fabsf(x));
  float r = __fdividef(1.0f - t, 1.0f + t);
  return copysignf(r, x);
}

// ---------------------------------------------------------------- weight pack
// g_Wp layout: [layer][kts(64)][bnb(8)][n(256)][k(32)] bf16 — each
// (kts,bnb) B-tile is a contiguous 16KB blob = LDS image [n][k].
// kts: 0-31 = Wx k-tiles, 32-63 = Wh k-tiles (k = (kts&31)*32 + kk).
// n-packing: b=n>>4, j=(b>>1)*16+(n&15); b even=tau, odd=forc.
__global__ void pack_weights(const float* __restrict__ w_state,
                             const float* __restrict__ w_input,
                             const float* __restrict__ w_tau,
                             const float* __restrict__ b_state,
                             const float* __restrict__ b_input,
                             const float* __restrict__ b_tau) {
  size_t idx = (size_t)blockIdx.x * blockDim.x + threadIdx.x;
  if (idx < (size_t)NLAYER * HD) {
    int l = (int)(idx >> 10), jj = (int)(idx & 1023);
    g_btau[idx]  = b_tau[l * HD + jj];
    g_bforc[idx] = b_state[l * HD + jj] + b_input[l * HD + jj];
  }
  const size_t total = (size_t)NLAYER * KSTORE * NPACK;
  if (idx >= total) return;
  int kk  = (int)(idx & 31);  size_t r = idx >> 5;
  int nn  = (int)(r & 255);   r >>= 8;
  int bnb = (int)(r & 7);     r >>= 3;
  int kts = (int)(r & 63);    r >>= 6;
  int layer = (int)r;
  int kb = kts >> 5;          // 0 = Wx, 1 = Wh
  int k  = (kts & 31) * 32 + kk;
  int n  = bnb * 256 + nn;
  int b  = n >> 4;
  int j  = (b >> 1) * 16 + (n & 15);
  bool is_tau = (b & 1) == 0;
  float wv;
  if (is_tau) wv = w_tau[(size_t)layer * HD * 2 * HD + (size_t)j * 2 * HD + (kb ? HD + k : k)];
  else        wv = kb ? w_state[(size_t)layer * HD * HD + (size_t)j * HD + k]
                      : w_input[(size_t)layer * HD * HD + (size_t)j * HD + k];
  g_Wp[idx] = __float2bfloat16(wv);
}

// ------------------------------------------------------------------- x split
__global__ void split_x(const float* __restrict__ x) {
  size_t i = (size_t)blockIdx.x * blockDim.x + threadIdx.x;
  if (i >= HN) return;
  float v = x[i];
  __hip_bfloat16 h16 = __float2bfloat16(v);
  g_xhi[i] = h16;
  g_xlo[i] = __float2bfloat16(v - __bfloat162float(h16));
}

__global__ void zero_h() {
  const size_t nvec = (size_t)NLAYER * HN / 8;
  bf16x8s z = {};
  for (size_t i = (size_t)blockIdx.x * blockDim.x + threadIdx.x;
       i < nvec; i += (size_t)gridDim.x * blockDim.x) {
    ((bf16x8s*)g_h_hi)[i] = z;
    ((bf16x8s*)g_h_lo)[i] = z;
  }
}

__global__ void init_ctrl() {
  if (threadIdx.x == 0) { g_ctrl.done = 0u; g_ctrl.t_conv = MAXT; }
  if (threadIdx.x < MAXT) g_ctrl.delta[threadIdx.x] = 0u;
}

// -------------------------------------------------------- fused GEMM + state
// Grid (32, 8): bx = m-panel, by = n-block. Linear id = by*32+bx -> XCD =
// bx%8: the 8 blocks sharing an A-panel land on one XCD's L2.
__launch_bounds__(512, 2)
__global__ void fused_step(int layer, int pin, int pout, int t) {
  if (g_ctrl.done) return;   // frozen after convergence (uniform, all exit)

  const __hip_bfloat16* cur_hi  = (layer == 0) ? g_xhi : &g_h_hi[((size_t)pout * NLAYER + (layer - 1)) * HN];
  const __hip_bfloat16* cur_lo  = (layer == 0) ? g_xlo : &g_h_lo[((size_t)pout * NLAYER + (layer - 1)) * HN];
  const __hip_bfloat16* h_hi_in = &g_h_hi[((size_t)pin * NLAYER + layer) * HN];
  const __hip_bfloat16* h_lo_in = &g_h_lo[((size_t)pin * NLAYER + layer) * HN];
  __hip_bfloat16* h_hi_out      = &g_h_hi[((size_t)pout * NLAYER + layer) * HN];
  __hip_bfloat16* h_lo_out      = &g_h_lo[((size_t)pout * NLAYER + layer) * HN];
  const __hip_bfloat16* Wpl     = &g_Wp[(size_t)layer * WP_PER_LAYER];
  const float* btau  = &g_btau[layer * HD];
  const float* bforc = &g_bforc[layer * HD];

  // 3-deep ring: 3 x (16KB A + 16KB B) = 96KB -> 1 block/CU (LDS-capped;
  // latency hidden by in-flight global_load_lds, not TLP)
  __shared__ __align__(16) __hip_bfloat16 Asm3[3][BM * BK];
  __shared__ __align__(16) __hip_bfloat16 Bsm3[3][BN * BK];

  const int tid  = threadIdx.x;
  const int lane = tid & 63;
  const int wave = tid >> 6;                 // 0..7
  const int wm = wave >> 2, wn = wave & 3;   // 2M x 4N wave grid
  const int m0 = blockIdx.x * BM;
  const int bn = blockIdx.y;                 // 0..7

  // stage K-tile T into ring buffer b: 4 gload_lds per wave (2 A + 2 B).
  // LDS chunk c = L*8+wave (1KB, wave-uniform base); lane writes base+lane*16B.
  // A chunk c covers rows [c*16, c*16+16): lane l -> row c*16+(l>>2),
  // k = kcol+(l&3)*8 (LDS [row][k], 64B rows). B: identity copy of packed blob.
  auto stage = [&](int T, int b) {
    const __hip_bfloat16* asrc;
    int pass = T >> 5;
    switch (pass) {                          // uniform
      case 0: asrc = cur_hi;  break;
      case 1: asrc = h_hi_in; break;
      case 2: asrc = cur_lo;  break;
      default: asrc = h_lo_in; break;
    }
    const int kcol = (T & 31) * BK;
    const int kts = ((pass & 1) << 5) + (T & 31);
    const __hip_bfloat16* bp = Wpl + ((size_t)kts * 8 + bn) * (BN * BK);
    #pragma unroll
    for (int L = 0; L < 2; ++L) {
      const int c = L * 8 + wave;
      gload_lds16(asrc + (size_t)(m0 + c * 16 + (lane >> 2)) * HD + kcol + (lane & 3) * 8,
                  &Asm3[b][c * 512]);
      gload_lds16(bp + c * 512 + lane * 8, &Bsm3[b][c * 512]);
    }
  };

  f32x4 acc[8][4] = {};

  // compute K-tile from ring buffer b: 12 ds_read_b128 + 32 MFMA.
  // Frag rows: A wm*128+fm*16+(lane&15), B wn*64+fn*16+(lane&15); k0=(lane>>4)*8.
  // 64B rows: bank-quads {0,4,..,28} tile all 32 banks, 8 lanes/quad,
  // 1024B/wave = 8 beats = the b128 floor -> conflict-free by layout.
  auto compute = [&](int b) {
    bf16x8s af[8], bfr[4];
    const int rsel = lane & 15, k0 = (lane >> 4) * 8;
    #pragma unroll
    for (int fm = 0; fm < 8; ++fm)
      af[fm] = *(const bf16x8s*)&Asm3[b][(wm * 128 + fm * 16 + rsel) * BK + k0];
    #pragma unroll
    for (int fn = 0; fn < 4; ++fn)
      bfr[fn] = *(const bf16x8s*)&Bsm3[b][(wn * 64 + fn * 16 + rsel) * BK + k0];
    __builtin_amdgcn_s_setprio(1);
    #pragma unroll
    for (int fm = 0; fm < 8; ++fm)
      #pragma unroll
      for (int fn = 0; fn < 4; ++fn)
        acc[fm][fn] = __builtin_amdgcn_mfma_f32_16x16x32_bf16(
            af[fm], bfr[fn], acc[fm][fn], 0, 0, 0);
    __builtin_amdgcn_s_setprio(0);
  };

  // prologue: tiles 0,1 in flight (8 loads/wave; vmcnt baseline 0 here)
  stage(0, 0);
  stage(1, 1);

  for (int T = 0; T < NKT - 1; ++T) {
    // vmcnt(4): retire tile T's 4 oldest loads (tile T+1's 4 stay in flight).
    // barrier: all waves' tile-T data published; all waves done reading
    // buffer (T+2)%3 (read at iter T-1) -> safe to overwrite after barrier.
    asm volatile("s_waitcnt vmcnt(4)" ::: "memory");
    __builtin_amdgcn_s_barrier();
    __builtin_amdgcn_sched_barrier(0);
    if (T < NKT - 2) stage(T + 2, (T + 2) % 3);
    compute(T % 3);
  }
  // peeled last iteration: only its own 4 loads outstanding -> exact drain.
  asm volatile("s_waitcnt vmcnt(0)" ::: "memory");
  __builtin_amdgcn_s_barrier();
  __builtin_amdgcn_sched_barrier(0);
  compute((NKT - 1) % 3);

  // ---- epilogue: C/D frag row=(lane>>4)*4+r2, col=lane&15.
  // fn even=tau, fn odd=forc for the same j = (bn*8+wn*2+p)*16+col.
  float lmax = 0.0f;
  const int col = lane & 15;
  const int rbase = (lane >> 4) * 4;
  #pragma unroll
  for (int fm = 0; fm < 8; ++fm) {
    #pragma unroll
    for (int p = 0; p < 2; ++p) {
      const int j = (bn * 8 + wn * 2 + p) * 16 + col;
      const float bt = btau[j], bfo = bforc[j];
      f32x4 tp = acc[fm][2 * p];
      f32x4 fp = acc[fm][2 * p + 1];
      #pragma unroll
      for (int r2 = 0; r2 < 4; ++r2) {
        const int m = m0 + wm * 128 + fm * 16 + rbase + r2;
        const size_t off = (size_t)m * HD + j;
        // stable_sigmoid(v) = 0.5*(tanh(v/2)+1)
        float tau  = 0.5f * (fast_tanh(0.5f * (tp[r2] + bt)) + 1.0f);
        float forc = fast_tanh(fp[r2] + bfo);
        float hold = __bfloat162float(h_hi_in[off]) + __bfloat162float(h_lo_in[off]);
        float hn = hold + DTC * (-hold / (tau + EPS_TAU_C) + forc);
        hn = fminf(10.0f, fmaxf(-10.0f, hn));
        lmax = fmaxf(lmax, fabsf(hn - hold));
        __hip_bfloat16 hhi = __float2bfloat16(hn);
        h_hi_out[off] = hhi;
        h_lo_out[off] = __float2bfloat16(hn - __bfloat162float(hhi));
      }
    }
  }
  #pragma unroll
  for (int s = 32; s; s >>= 1) lmax = fmaxf(lmax, __shfl_xor(lmax, s, 64));
  if (lane == 0) atomicMax(&g_ctrl.delta[t], __float_as_uint(lmax));
}

__global__ void check_step(int t) {
  if (threadIdx.x != 0) return;
  if (g_ctrl.done) return;
  if (__uint_as_float(g_ctrl.delta[t]) < EPS_CONV_C) { g_ctrl.done = 1u; g_ctrl.t_conv = t; }
}

__global__ void write_out(float* __restrict__ out, int out_size) {
  size_t i = (size_t)blockIdx.x * blockDim.x + threadIdx.x;
  if (i >= (size_t)out_size) return;
  int tc = g_ctrl.t_conv;
  int last = (tc >= MAXT) ? (MAXT - 1) : tc;
  int par = (last + 1) & 1;                  // parity buffer holding final state
  const __hip_bfloat16* hh = &g_h_hi[((size_t)par * NLAYER + (NLAYER - 1)) * HN];
  const __hip_bfloat16* hl = &g_h_lo[((size_t)par * NLAYER + (NLAYER - 1)) * HN];
  if (i == (size_t)(out_size - 1)) {
    out[i] = (float)tc;                      // t_conv (float-promoted concat)
  } else if (i < HN) {
    out[i] = __bfloat162float(hh[i]) + __bfloat162float(hl[i]);
  }
}

// -------------------------------------------------------------------- launch
extern "C" void kernel_launch(void* const* d_in, const int* in_sizes, int n_in,
                              void* d_out, int out_size, void* d_ws, size_t ws_size,
                              hipStream_t stream) {
  const float* x       = (const float*)d_in[0];
  const float* w_state = (const float*)d_in[1];
  const float* b_state = (const float*)d_in[2];
  const float* w_input = (const float*)d_in[3];
  const float* b_input = (const float*)d_in[4];
  const float* w_tau   = (const float*)d_in[5];
  const float* b_tau   = (const float*)d_in[6];
  (void)d_ws; (void)ws_size; (void)in_sizes; (void)n_in;

  {
    size_t total = (size_t)NLAYER * KSTORE * NPACK;
    pack_weights<<<dim3((unsigned)((total + 255) / 256)), dim3(256), 0, stream>>>(
        w_state, w_input, w_tau, b_state, b_input, b_tau);
  }
  split_x<<<dim3((unsigned)((HN + 255) / 256)), dim3(256), 0, stream>>>(x);
  zero_h<<<dim3(2048), dim3(256), 0, stream>>>();
  init_ctrl<<<dim3(1), dim3(64), 0, stream>>>();

  for (int t = 0; t < MAXT; ++t) {
    const int pin = t & 1, pout = 1 - pin;
    for (int l = 0; l < NLAYER; ++l) {
      fused_step<<<dim3(32, 8), dim3(512), 0, stream>>>(l, pin, pout, t);
    }
    check_step<<<dim3(1), dim3(64), 0, stream>>>(t);
  }

  write_out<<<dim3((unsigned)((HN + 256) / 256)), dim3(256), 0, stream>>>(
      (float*)d_out, out_size);
}